// Round 1
// baseline (4280.066 us; speedup 1.0000x reference)
//
#include <hip/hip_runtime.h>
#include <math.h>

#define NTHREADS 256
#define BR 64

// ---- Compile-time hash-grid constants (derived from reference formulas) ----
// S = 2^(7/15); scale[l] = 16*S^l - 1  (f32)
__device__ __constant__ float c_scale[16] = {
    15.0f,        21.110607f,  29.554930f,  41.224254f,
    57.350239f,   79.634946f,  110.430473f, 152.987205f,
    211.796890f,  293.066769f, 405.374657f, 560.574388f,
    775.046906f,  1071.429232f, 1481.003616f, 2047.0f
};
// offsets = cumsum of per-level sizes (dense 0-4: 4920,13824,32768,85184,216000; hashed: 524288 each)
__device__ __constant__ unsigned c_off[16] = {
    0u,        4920u,     18744u,    51512u,
    136696u,   352696u,   876984u,   1401272u,
    1925560u,  2449848u,  2974136u,  3498424u,
    4022712u,  4547000u,  5071288u,  5595576u
};
// res+1 for dense levels 0..4 (hashed levels never use it)
__device__ __constant__ unsigned c_res1[16] = {
    17u, 24u, 32u, 44u, 60u, 0u,0u,0u,0u,0u,0u,0u,0u,0u,0u,0u
};

__global__ __launch_bounds__(NTHREADS, 2)
void fused_hashmlp(const float* __restrict__ x, const float* __restrict__ table,
                   const float* __restrict__ w1, const float* __restrict__ b1,
                   const float* __restrict__ w2, const float* __restrict__ b2,
                   const float* __restrict__ w3, const float* __restrict__ b3,
                   const float* __restrict__ w4, const float* __restrict__ b4,
                   float* __restrict__ out, int N)
{
    __shared__ float sX[BR][3];
    __shared__ float sF[BR][33];    // padded: conflict-free column reads
    __shared__ float sH[BR][257];   // padded: conflict-free column reads

    const int tid = threadIdx.x;
    const int p0 = blockIdx.x * BR;
    if (p0 >= N) return;

    // ---- load coords ----
    if (tid < BR * 3) {
        int gi = p0 * 3 + tid;
        if (gi < N * 3) sX[tid / 3][tid % 3] = x[gi];
    }
    __syncthreads();

    // ---- hash-grid encode: 64 points x 16 levels = 1024 tasks, 4 per thread ----
    #pragma unroll
    for (int it = 0; it < 4; ++it) {
        const int task = tid + NTHREADS * it;
        const int p = task >> 4;
        const int l = task & 15;
        const float sc = c_scale[l];
        const float inv = 1.0f / 1.5f;
        const float px = sX[p][0] * inv * sc + 0.5f;
        const float py = sX[p][1] * inv * sc + 0.5f;
        const float pz = sX[p][2] * inv * sc + 0.5f;
        const float fx = floorf(px), fy = floorf(py), fz = floorf(pz);
        const float rx = px - fx, ry = py - fy, rz = pz - fz;
        const unsigned ux = (unsigned)fx, uy = (unsigned)fy, uz = (unsigned)fz;
        const unsigned off = c_off[l];
        const unsigned r1 = c_res1[l];
        const bool dense = (l < 5);
        float ax = 0.0f, ay = 0.0f;
        #pragma unroll
        for (int c = 0; c < 8; ++c) {
            const unsigned bx = c & 1, by = (c >> 1) & 1, bz = (c >> 2) & 1;
            const unsigned cx = ux + bx, cy = uy + by, cz = uz + bz;
            const float wx = bx ? rx : (1.0f - rx);
            const float wy = by ? ry : (1.0f - ry);
            const float wz = bz ? rz : (1.0f - rz);
            const float w = wx * wy * wz;
            unsigned idx;
            if (dense) idx = cx + cy * r1 + cz * r1 * r1;
            else       idx = (cx ^ (cy * 2654435761u) ^ (cz * 805459861u)) & 524287u;
            const float2 tv = *reinterpret_cast<const float2*>(table + 2u * (idx + off));
            ax = fmaf(w, tv.x, ax);
            ay = fmaf(w, tv.y, ay);
        }
        sF[p][2 * l + 0] = ax;
        sF[p][2 * l + 1] = ay;
    }
    __syncthreads();

    // ---- MLP: each thread owns rows r0..r0+3, cols c0..c0+15 ----
    const int rg = tid >> 4;          // 0..15
    const int cgp = tid & 15;         // 0..15
    const int r0 = rg * 4;
    const int c0 = cgp * 16;

    float acc[4][16];

    // ---- layer 1: [64,32] @ [32,256], relu -> sH ----
    #pragma unroll
    for (int i = 0; i < 4; ++i)
        #pragma unroll
        for (int j = 0; j < 16; ++j) acc[i][j] = 0.0f;

    for (int k = 0; k < 32; ++k) {
        const float a0 = sF[r0 + 0][k];
        const float a1 = sF[r0 + 1][k];
        const float a2 = sF[r0 + 2][k];
        const float a3 = sF[r0 + 3][k];
        const float4* wp = reinterpret_cast<const float4*>(w1 + k * 256 + c0);
        const float4 v0 = wp[0], v1 = wp[1], v2 = wp[2], v3 = wp[3];
        const float bv[16] = { v0.x, v0.y, v0.z, v0.w, v1.x, v1.y, v1.z, v1.w,
                               v2.x, v2.y, v2.z, v2.w, v3.x, v3.y, v3.z, v3.w };
        #pragma unroll
        for (int j = 0; j < 16; ++j) {
            acc[0][j] = fmaf(a0, bv[j], acc[0][j]);
            acc[1][j] = fmaf(a1, bv[j], acc[1][j]);
            acc[2][j] = fmaf(a2, bv[j], acc[2][j]);
            acc[3][j] = fmaf(a3, bv[j], acc[3][j]);
        }
    }
    {
        const float4* bp = reinterpret_cast<const float4*>(b1 + c0);
        const float4 u0 = bp[0], u1 = bp[1], u2 = bp[2], u3 = bp[3];
        const float bb[16] = { u0.x, u0.y, u0.z, u0.w, u1.x, u1.y, u1.z, u1.w,
                               u2.x, u2.y, u2.z, u2.w, u3.x, u3.y, u3.z, u3.w };
        #pragma unroll
        for (int i = 0; i < 4; ++i)
            #pragma unroll
            for (int j = 0; j < 16; ++j)
                sH[r0 + i][c0 + j] = fmaxf(acc[i][j] + bb[j], 0.0f);
    }
    __syncthreads();

    // ---- hidden layers 2 & 3: [64,256] @ [256,256], relu -> sH (in place after full read) ----
    for (int layer = 0; layer < 2; ++layer) {
        const float* W = (layer == 0) ? w2 : w3;
        const float* B = (layer == 0) ? b2 : b3;

        #pragma unroll
        for (int i = 0; i < 4; ++i)
            #pragma unroll
            for (int j = 0; j < 16; ++j) acc[i][j] = 0.0f;

        for (int k = 0; k < 256; ++k) {
            const float a0 = sH[r0 + 0][k];
            const float a1 = sH[r0 + 1][k];
            const float a2 = sH[r0 + 2][k];
            const float a3 = sH[r0 + 3][k];
            const float4* wp = reinterpret_cast<const float4*>(W + k * 256 + c0);
            const float4 v0 = wp[0], v1 = wp[1], v2 = wp[2], v3 = wp[3];
            const float bv[16] = { v0.x, v0.y, v0.z, v0.w, v1.x, v1.y, v1.z, v1.w,
                                   v2.x, v2.y, v2.z, v2.w, v3.x, v3.y, v3.z, v3.w };
            #pragma unroll
            for (int j = 0; j < 16; ++j) {
                acc[0][j] = fmaf(a0, bv[j], acc[0][j]);
                acc[1][j] = fmaf(a1, bv[j], acc[1][j]);
                acc[2][j] = fmaf(a2, bv[j], acc[2][j]);
                acc[3][j] = fmaf(a3, bv[j], acc[3][j]);
            }
        }
        __syncthreads();   // everyone done READING sH before overwrite
        {
            const float4* bp = reinterpret_cast<const float4*>(B + c0);
            const float4 u0 = bp[0], u1 = bp[1], u2 = bp[2], u3 = bp[3];
            const float bb[16] = { u0.x, u0.y, u0.z, u0.w, u1.x, u1.y, u1.z, u1.w,
                                   u2.x, u2.y, u2.z, u2.w, u3.x, u3.y, u3.z, u3.w };
            #pragma unroll
            for (int i = 0; i < 4; ++i)
                #pragma unroll
                for (int j = 0; j < 16; ++j)
                    sH[r0 + i][c0 + j] = fmaxf(acc[i][j] + bb[j], 0.0f);
        }
        __syncthreads();
    }

    // ---- layer 4: [64,256] @ [256,3] + sigmoid ----
    if (tid < BR * 3) {
        const int r = tid / 3;
        const int c = tid - 3 * r;
        float a4 = 0.0f;
        for (int k = 0; k < 256; ++k)
            a4 = fmaf(sH[r][k], w4[k * 3 + c], a4);
        const float z = a4 + b4[c];
        const int pi = p0 + r;
        if (pi < N)
            out[pi * 3 + c] = 1.0f / (1.0f + expf(-z));
    }
}

extern "C" void kernel_launch(void* const* d_in, const int* in_sizes, int n_in,
                              void* d_out, int out_size, void* d_ws, size_t ws_size,
                              hipStream_t stream) {
    const float* x     = (const float*)d_in[0];
    const float* table = (const float*)d_in[1];
    const float* w1    = (const float*)d_in[2];
    const float* b1    = (const float*)d_in[3];
    const float* w2    = (const float*)d_in[4];
    const float* b2    = (const float*)d_in[5];
    const float* w3    = (const float*)d_in[6];
    const float* b3    = (const float*)d_in[7];
    const float* w4    = (const float*)d_in[8];
    const float* b4    = (const float*)d_in[9];
    float* out = (float*)d_out;

    const int N = in_sizes[0] / 3;
    const int grid = (N + BR - 1) / BR;
    hipLaunchKernelGGL(fused_hashmlp, dim3(grid), dim3(NTHREADS), 0, stream,
                       x, table, w1, b1, w2, b2, w3, b3, w4, b4, out, N);
}

// Round 3
// 843.698 us; speedup vs baseline: 5.0730x; 5.0730x over previous
//
#include <hip/hip_runtime.h>
#include <hip/hip_bf16.h>
#include <math.h>

#define NTHREADS 256
#define BR 64

typedef __attribute__((ext_vector_type(8))) short   s16x8;
typedef __attribute__((ext_vector_type(8))) __bf16  bf16x8;
typedef __attribute__((ext_vector_type(4))) float   f32x4;

// ---- Compile-time hash-grid constants (verified exact in round 1: absmax 0.0) ----
__device__ __constant__ float c_scale[16] = {
    15.0f,        21.110607f,  29.554930f,  41.224254f,
    57.350239f,   79.634946f,  110.430473f, 152.987205f,
    211.796890f,  293.066769f, 405.374657f, 560.574388f,
    775.046906f,  1071.429232f, 1481.003616f, 2047.0f
};
__device__ __constant__ unsigned c_off[16] = {
    0u,        4920u,     18744u,    51512u,
    136696u,   352696u,   876984u,   1401272u,
    1925560u,  2449848u,  2974136u,  3498424u,
    4022712u,  4547000u,  5071288u,  5595576u
};
__device__ __constant__ unsigned c_res1[16] = {
    17u, 24u, 32u, 44u, 60u, 0u,0u,0u,0u,0u,0u,0u,0u,0u,0u,0u
};

__device__ inline unsigned short f2bf(float f) {
    unsigned u = __builtin_bit_cast(unsigned, f);
    u += 0x7FFFu + ((u >> 16) & 1u);          // round-to-nearest-even
    return (unsigned short)(u >> 16);
}
__device__ inline float bf2f(unsigned short h) {
    unsigned u = ((unsigned)h) << 16;
    return __builtin_bit_cast(float, u);
}
__device__ inline f32x4 mfma_bf16(s16x8 a, s16x8 b, f32x4 c) {
    return __builtin_amdgcn_mfma_f32_16x16x32_bf16(
        __builtin_bit_cast(bf16x8, a), __builtin_bit_cast(bf16x8, b), c, 0, 0, 0);
}

// ws layout (bf16 elements): wt1[256][32] @0 ; wt2[256][256] @8192 ; wt3[256][256] @73728 ;
// then (optional) bf16 table @139264.  All transposed: wt[col][k] = w[k][col].
__global__ void convert_w(const float* __restrict__ w1, const float* __restrict__ w2,
                          const float* __restrict__ w3, unsigned short* __restrict__ ws) {
    int t = blockIdx.x * blockDim.x + threadIdx.x;
    if (t < 8192) {
        int col = t >> 5, k = t & 31;
        ws[t] = f2bf(w1[k * 256 + col]);
    } else if (t < 73728) {
        int u = t - 8192; int col = u >> 8, k = u & 255;
        ws[t] = f2bf(w2[k * 256 + col]);
    } else if (t < 139264) {
        int u = t - 73728; int col = u >> 8, k = u & 255;
        ws[t] = f2bf(w3[k * 256 + col]);
    }
}

__global__ void convert_table(const float* __restrict__ t, unsigned short* __restrict__ o, int n4) {
    int i = blockIdx.x * blockDim.x + threadIdx.x;
    if (i < n4) {
        float4 v = ((const float4*)t)[i];
        ushort4 r;
        r.x = f2bf(v.x); r.y = f2bf(v.y); r.z = f2bf(v.z); r.w = f2bf(v.w);
        ((ushort4*)o)[i] = r;
    }
}

template<bool BFT>
__global__ __launch_bounds__(NTHREADS, 3)
void fused_hashmlp(const float* __restrict__ x, const float* __restrict__ table,
                   const unsigned short* __restrict__ tbf,
                   const unsigned short* __restrict__ wt,
                   const float* __restrict__ b1, const float* __restrict__ b2,
                   const float* __restrict__ b3,
                   const float* __restrict__ w4, const float* __restrict__ b4,
                   float* __restrict__ out, int N)
{
    __shared__ float sX[BR][3];
    __shared__ unsigned short sA[BR * 256];   // 32 KB activation buffer, rows of 512B, XOR-swizzled

    const int tid = threadIdx.x;
    const int p0  = blockIdx.x * BR;
    if (p0 >= N) return;
    char* sAb = (char*)sA;

    if (tid < BR * 3) sX[tid / 3][tid % 3] = x[p0 * 3 + tid];
    __syncthreads();

    // ---- hash-grid encode: task = it*256+tid ; level l = task>>6 is WAVE-UNIFORM ----
    #pragma unroll
    for (int it = 0; it < 4; ++it) {
        const int task = it * NTHREADS + tid;
        const int l = task >> 6;          // wave-uniform
        const int p = task & 63;          // == lane
        const float sc  = c_scale[l];
        const float inv = (1.0f / 1.5f);
        const float px = sX[p][0] * inv * sc + 0.5f;
        const float py = sX[p][1] * inv * sc + 0.5f;
        const float pz = sX[p][2] * inv * sc + 0.5f;
        const float fx = floorf(px), fy = floorf(py), fz = floorf(pz);
        const float rx = px - fx, ry = py - fy, rz = pz - fz;
        const unsigned ux = (unsigned)fx, uy = (unsigned)fy, uz = (unsigned)fz;
        const unsigned off = c_off[l];
        const unsigned r1  = c_res1[l];
        const bool dense = (l < 5);       // wave-uniform branch
        float ax = 0.0f, ay = 0.0f;
        #pragma unroll
        for (int c = 0; c < 8; ++c) {
            const unsigned bx = c & 1, by = (c >> 1) & 1, bz = (c >> 2) & 1;
            const unsigned cx = ux + bx, cy = uy + by, cz = uz + bz;
            const float wx = bx ? rx : (1.0f - rx);
            const float wy = by ? ry : (1.0f - ry);
            const float wz = bz ? rz : (1.0f - rz);
            const float w = wx * wy * wz;
            unsigned idx;
            if (dense) idx = cx + cy * r1 + cz * r1 * r1;
            else       idx = (cx ^ (cy * 2654435761u) ^ (cz * 805459861u)) & 524287u;
            float tx, ty;
            if (BFT) {
                const unsigned v = *reinterpret_cast<const unsigned*>(tbf + 2u * (idx + off));
                tx = bf2f((unsigned short)(v & 0xFFFFu));
                ty = bf2f((unsigned short)(v >> 16));
            } else {
                const float2 tv = *reinterpret_cast<const float2*>(table + 2u * (idx + off));
                tx = tv.x; ty = tv.y;
            }
            ax = fmaf(w, tx, ax);
            ay = fmaf(w, ty, ay);
        }
        // write features (cols 2l, 2l+1) as packed bf16x2 into swizzled A buffer
        const unsigned pack = (unsigned)f2bf(ax) | ((unsigned)f2bf(ay) << 16);
        *reinterpret_cast<unsigned*>(sAb + p * 512 + ((l * 4) ^ ((p & 7) << 4))) = pack;
    }
    __syncthreads();

    // ---- MFMA MLP ----
    const int lane = tid & 63;
    const int wid  = tid >> 6;
    const int colb = wid * 64;           // wave's 64-column slice
    const int arow = lane & 15;          // A fragment row (within 16-row tile)
    const int kgrp = lane >> 4;          // 0..3 : k-offset group (k0 = kgrp*8)
    const int bcol = lane & 15;          // B fragment col

    f32x4 acc[4][4];

    auto epilogue = [&](const float* __restrict__ bias) {
        float bv[4];
        #pragma unroll
        for (int ct = 0; ct < 4; ++ct) bv[ct] = bias[colb + ct * 16 + bcol];
        #pragma unroll
        for (int rt = 0; rt < 4; ++rt) {
            #pragma unroll
            for (int r = 0; r < 4; ++r) {
                const int row = rt * 16 + kgrp * 4 + r;
                char* rp = sAb + row * 512;
                const unsigned sw = (unsigned)((row & 7) << 4);
                #pragma unroll
                for (int ct = 0; ct < 4; ++ct) {
                    const int col = colb + ct * 16 + bcol;
                    const float v = fmaxf(acc[rt][ct][r] + bv[ct], 0.0f);
                    *reinterpret_cast<unsigned short*>(rp + (((unsigned)(col * 2)) ^ sw)) = f2bf(v);
                }
            }
        }
    };

    // ---- layer 1: [64,32] @ wt1 -> relu -> sA ----
    {
        #pragma unroll
        for (int rt = 0; rt < 4; ++rt)
            #pragma unroll
            for (int ct = 0; ct < 4; ++ct) acc[rt][ct] = f32x4{0.f, 0.f, 0.f, 0.f};

        s16x8 afr[4];
        #pragma unroll
        for (int rt = 0; rt < 4; ++rt) {
            const int row = rt * 16 + arow;
            afr[rt] = *reinterpret_cast<const s16x8*>(
                sAb + row * 512 + (((unsigned)(kgrp * 16)) ^ ((unsigned)((row & 7) << 4))));
        }
        #pragma unroll
        for (int ct = 0; ct < 4; ++ct) {
            const int col = colb + ct * 16 + bcol;
            const s16x8 bfr = *reinterpret_cast<const s16x8*>(wt + col * 32 + kgrp * 8);
            #pragma unroll
            for (int rt = 0; rt < 4; ++rt)
                acc[rt][ct] = mfma_bf16(afr[rt], bfr, acc[rt][ct]);
        }
        __syncthreads();
        epilogue(b1);
        __syncthreads();
    }

    // ---- layers 2 & 3: [64,256] @ wt -> relu -> sA ----
    #pragma unroll 1
    for (int layer = 0; layer < 2; ++layer) {
        const unsigned short* __restrict__ W = wt + 8192 + (layer << 16);
        #pragma unroll
        for (int rt = 0; rt < 4; ++rt)
            #pragma unroll
            for (int ct = 0; ct < 4; ++ct) acc[rt][ct] = f32x4{0.f, 0.f, 0.f, 0.f};

        for (int ks = 0; ks < 8; ++ks) {
            s16x8 afr[4];
            #pragma unroll
            for (int rt = 0; rt < 4; ++rt) {
                const int row = rt * 16 + arow;
                afr[rt] = *reinterpret_cast<const s16x8*>(
                    sAb + row * 512 + (((unsigned)(ks * 64 + kgrp * 16)) ^ ((unsigned)((row & 7) << 4))));
            }
            #pragma unroll
            for (int ct = 0; ct < 4; ++ct) {
                const s16x8 bfr = *reinterpret_cast<const s16x8*>(
                    W + (colb + ct * 16 + bcol) * 256 + ks * 32 + kgrp * 8);
                #pragma unroll
                for (int rt = 0; rt < 4; ++rt)
                    acc[rt][ct] = mfma_bf16(afr[rt], bfr, acc[rt][ct]);
            }
        }
        __syncthreads();
        epilogue(layer == 0 ? b2 : b3);
        __syncthreads();
    }

    // ---- layer 4: [64,256] @ [256,3] + sigmoid ----
    if (tid < BR * 3) {
        const int r = tid / 3;
        const int c = tid - 3 * r;
        float z = 0.0f;
        for (int kb = 0; kb < 32; ++kb) {
            const s16x8 hv = *reinterpret_cast<const s16x8*>(
                sAb + r * 512 + (((unsigned)(kb * 16)) ^ ((unsigned)((r & 7) << 4))));
            #pragma unroll
            for (int j = 0; j < 8; ++j) {
                const unsigned short hb = (unsigned short)hv[j];
                z = fmaf(bf2f(hb), w4[(kb * 8 + j) * 3 + c], z);
            }
        }
        z += b4[c];
        const int pi = p0 + r;
        if (pi < N) out[pi * 3 + c] = 1.0f / (1.0f + expf(-z));
    }
}

extern "C" void kernel_launch(void* const* d_in, const int* in_sizes, int n_in,
                              void* d_out, int out_size, void* d_ws, size_t ws_size,
                              hipStream_t stream) {
    const float* x     = (const float*)d_in[0];
    const float* table = (const float*)d_in[1];
    const float* w1    = (const float*)d_in[2];
    const float* b1    = (const float*)d_in[3];
    const float* w2    = (const float*)d_in[4];
    const float* b2    = (const float*)d_in[5];
    const float* w3    = (const float*)d_in[6];
    const float* b3    = (const float*)d_in[7];
    const float* w4    = (const float*)d_in[8];
    const float* b4    = (const float*)d_in[9];
    float* out = (float*)d_out;

    const int N = in_sizes[0] / 3;
    const int grid = (N + BR - 1) / BR;

    const size_t W_ELEMS   = 139264;            // bf16 weight elements
    const size_t TBL_ELEMS = 12239728;          // 2 * TOTAL bf16 table elements
    const size_t need_full = (W_ELEMS + TBL_ELEMS) * 2;

    unsigned short* wsw = (unsigned short*)d_ws;
    unsigned short* tbf = wsw + W_ELEMS;

    hipLaunchKernelGGL(convert_w, dim3(544), dim3(256), 0, stream, w1, w2, w3, wsw);

    if (ws_size >= need_full) {
        const size_t n4 = TBL_ELEMS / 4;
        hipLaunchKernelGGL(convert_table, dim3((unsigned)((n4 + 255) / 256)), dim3(256), 0, stream,
                           table, tbf, (int)n4);
        hipLaunchKernelGGL(fused_hashmlp<true>, dim3(grid), dim3(NTHREADS), 0, stream,
                           x, table, tbf, wsw, b1, b2, b3, w4, b4, out, N);
    } else {
        hipLaunchKernelGGL(fused_hashmlp<false>, dim3(grid), dim3(NTHREADS), 0, stream,
                           x, table, tbf, wsw, b1, b2, b3, w4, b4, out, N);
    }
}